// Round 12
// baseline (314.011 us; speedup 1.0000x reference)
//
#include <hip/hip_runtime.h>
#include <hip/hip_bf16.h>

// Decoder loss: keep-mask (kth-value threshold + local max), BCE coord loss,
// bidirectional NN recolor + L1 rgb loss.
// L=16384 candidates, N=10000 targets, K=8 (collapses to argmin; R1-proven).
// R12: EXACT spatial-grid NN replaces brute force. Rules learned:
//   - Brute-force scan plateaus 42-48us across 3 structures (R8/R10/R11):
//     the O(N*kc)=184M eval count is the floor. Break the algorithm.
//   - grid.sync ~40us (R4); mass __threadfence ~0.4ms (R7); spin-fusion
//     neutral (R9). Kernel boundary ~5us is the cheap sync.
//   - 16^3 grid, counting sort, expanding-ring search with exact conservative
//     termination bound; ring loop bounded (R<=16) -> guaranteed exit.

typedef unsigned long long ull;
#define GR 16   // grid resolution per axis

// ---- grid helpers ----------------------------------------------------------
__device__ __forceinline__ int cell_clamp(float v, float b0, float ih) {
  int c = (int)((v - b0) * ih);
  return min(max(c, 0), GR - 1);
}
__device__ __forceinline__ int cell_of(float x, float y, float z,
                                       const float* gp) {
  int cx = cell_clamp(x, gp[0], gp[6]);
  int cy = cell_clamp(y, gp[1], gp[7]);
  int cz = cell_clamp(z, gp[2], gp[8]);
  return (cz * GR + cy) * GR + cx;
}

// exact NN via expanding Chebyshev rings; conservative termination.
__device__ void nn_search(
    float qx, float qy, float qz,
    const int* __restrict__ start, const float4* __restrict__ pts,
    const float* gp, float* obest, int* oidx) {
  float bx0 = gp[0], by0 = gp[1], bz0 = gp[2];
  float hx = gp[3], hy = gp[4], hz = gp[5];
  int cx = cell_clamp(qx, bx0, gp[6]);
  int cy = cell_clamp(qy, by0, gp[7]);
  int cz = cell_clamp(qz, bz0, gp[8]);
  float best = 3e38f; int bi = 0;
  for (int R = 0; R <= GR; ++R) {
    int zlo = max(cz - R, 0), zhi = min(cz + R, GR - 1);
    int ylo = max(cy - R, 0), yhi = min(cy + R, GR - 1);
    int xlo = max(cx - R, 0), xhi = min(cx + R, GR - 1);
    for (int zz = zlo; zz <= zhi; ++zz) {
      int adz = (zz > cz) ? zz - cz : cz - zz;
      for (int yy = ylo; yy <= yhi; ++yy) {
        int ady = (yy > cy) ? yy - cy : cy - yy;
        bool face = (adz == R) || (ady == R);
        for (int xx = xlo; xx <= xhi; ++xx) {
          int adx = (xx > cx) ? xx - cx : cx - xx;
          if (!face && adx != R) continue;   // only the shell at radius R
          int cid = (zz * GR + yy) * GR + xx;
          int s = start[cid], e = start[cid + 1];
          for (int p = s; p < e; ++p) {
            float4 P = pts[p];
            float dx = qx - P.x, dy = qy - P.y, dz = qz - P.z;
            float d = fmaf(dx, dx, fmaf(dy, dy, dz * dz));  // R1-proven formula
            if (d < best) { best = d; bi = __float_as_int(P.w); }
          }
        }
      }
    }
    // min distance from q to unexplored region (grid \ B_R), per-axis slabs
    float dmin = 3e38f;
    if (cx - R > 0)      dmin = fminf(dmin, qx - (bx0 + (cx - R) * hx));
    if (cx + R < GR - 1) dmin = fminf(dmin, (bx0 + (cx + R + 1) * hx) - qx);
    if (cy - R > 0)      dmin = fminf(dmin, qy - (by0 + (cy - R) * hy));
    if (cy + R < GR - 1) dmin = fminf(dmin, (by0 + (cy + R + 1) * hy) - qy);
    if (cz - R > 0)      dmin = fminf(dmin, qz - (bz0 + (cz - R) * hz));
    if (cz + R < GR - 1) dmin = fminf(dmin, (bz0 + (cz + R + 1) * hz) - qz);
    if (dmin == 3e38f) break;             // whole grid explored
    float dm = fmaxf(dmin, 0.f);
    if (dm * dm >= best) break;           // nothing outside can beat best
  }
  *obest = best; *oidx = bi;
}

// ---- Kernel 1: init + keys + local max + hist-zero + per-block bbox --------
__global__ __launch_bounds__(256) void k_prep(
    const float* __restrict__ pred, const float* __restrict__ txyz,
    const float* __restrict__ cxyz, float4* __restrict__ numden,
    int* __restrict__ zerohit, unsigned int* __restrict__ key,
    unsigned char* __restrict__ islm, unsigned int* __restrict__ chist,
    unsigned int* __restrict__ thist, float4* __restrict__ blockmin,
    float4* __restrict__ blockmax, int* __restrict__ counters,
    float* __restrict__ out, int L, int N) {
  __shared__ float bmn[4][3], bmx[4][3];
  int tid = threadIdx.x, lane = tid & 63, wv = tid >> 6;
  int gidx = blockIdx.x * 256 + tid;
  int gsz = (int)gridDim.x * 256;
  float mnx = 3e38f, mny = 3e38f, mnz = 3e38f;
  float mxx = -3e38f, mxy = -3e38f, mxz = -3e38f;
  for (int i = gidx; i < N; i += gsz) {
    float x = txyz[3*i], y = txyz[3*i+1], z = txyz[3*i+2];
    mnx = fminf(mnx, x); mny = fminf(mny, y); mnz = fminf(mnz, z);
    mxx = fmaxf(mxx, x); mxy = fmaxf(mxy, y); mxz = fmaxf(mxz, z);
  }
  for (int i = gidx; i < L; i += gsz) {
    float x = cxyz[3*i], y = cxyz[3*i+1], z = cxyz[3*i+2];
    mnx = fminf(mnx, x); mny = fminf(mny, y); mnz = fminf(mnz, z);
    mxx = fmaxf(mxx, x); mxy = fmaxf(mxy, y); mxz = fmaxf(mxz, z);
    numden[i] = make_float4(0.f, 0.f, 0.f, 0.f);
    zerohit[i] = 0;
  }
  for (int i = gidx; i < GR*GR*GR; i += gsz) { chist[i] = 0u; thist[i] = 0u; }
  if (gidx < 8) counters[gidx] = 0;
  if (gidx < 2) out[gidx] = 0.f;
  int ngroups = L >> 3;
  for (int g = gidx; g < ngroups; g += gsz) {
    const float4* pv = (const float4*)pred + (size_t)g * 2;
    float4 a = pv[0], b = pv[1];
    float v[8] = {a.x, a.y, a.z, a.w, b.x, b.y, b.z, b.w};
    int bi = 0; float bv = v[0];
    #pragma unroll
    for (int j = 1; j < 8; ++j) if (v[j] > bv) { bv = v[j]; bi = j; }
    unsigned int kk[8];
    ull lmpack = 0ull;
    #pragma unroll
    for (int j = 0; j < 8; ++j) {
      unsigned int fb = __float_as_uint(v[j]);
      unsigned int mk = (fb & 0x80000000u) ? ~fb : (fb | 0x80000000u);
      if (j == bi) { mk = 0xFF800000u; lmpack |= 1ull << (8 * j); }  // +inf
      kk[j] = mk;
    }
    ((uint4*)key)[g*2]   = make_uint4(kk[0], kk[1], kk[2], kk[3]);
    ((uint4*)key)[g*2+1] = make_uint4(kk[4], kk[5], kk[6], kk[7]);
    *(ull*)(islm + (size_t)g * 8) = lmpack;
  }
  // block bbox reduce (wave shfl then LDS across 4 waves)
  #pragma unroll
  for (int o = 32; o > 0; o >>= 1) {
    mnx = fminf(mnx, __shfl_xor(mnx, o)); mny = fminf(mny, __shfl_xor(mny, o));
    mnz = fminf(mnz, __shfl_xor(mnz, o)); mxx = fmaxf(mxx, __shfl_xor(mxx, o));
    mxy = fmaxf(mxy, __shfl_xor(mxy, o)); mxz = fmaxf(mxz, __shfl_xor(mxz, o));
  }
  if (lane == 0) {
    bmn[wv][0] = mnx; bmn[wv][1] = mny; bmn[wv][2] = mnz;
    bmx[wv][0] = mxx; bmx[wv][1] = mxy; bmx[wv][2] = mxz;
  }
  __syncthreads();
  if (tid == 0) {
    for (int w = 1; w < 4; ++w) {
      bmn[0][0] = fminf(bmn[0][0], bmn[w][0]);
      bmn[0][1] = fminf(bmn[0][1], bmn[w][1]);
      bmn[0][2] = fminf(bmn[0][2], bmn[w][2]);
      bmx[0][0] = fmaxf(bmx[0][0], bmx[w][0]);
      bmx[0][1] = fmaxf(bmx[0][1], bmx[w][1]);
      bmx[0][2] = fmaxf(bmx[0][2], bmx[w][2]);
    }
    blockmin[blockIdx.x] = make_float4(bmn[0][0], bmn[0][1], bmn[0][2], 0.f);
    blockmax[blockIdx.x] = make_float4(bmx[0][0], bmx[0][1], bmx[0][2], 0.f);
  }
}

// ---- helper: pick bin containing rank from LDS hist (wave 0) ---------------
__device__ __forceinline__ void select_bin(
    unsigned int* hist, int nb, unsigned int rank,
    unsigned int* sB, unsigned int* sR, int tid) {
  if (tid < 64) {
    int g = nb >> 6;
    unsigned int sum = 0;
    for (int j = 0; j < g; ++j) sum += hist[tid * g + j];
    unsigned int incl = sum;
    for (int o = 1; o < 64; o <<= 1) {
      unsigned int v = __shfl_up(incl, o);
      if (tid >= o) incl += v;
    }
    unsigned int excl = incl - sum;
    bool cond = (rank >= excl) && (rank < incl);
    unsigned long long bal = __ballot(cond);
    int first = __ffsll((long long)bal) - 1;
    if (tid == first) {
      unsigned int r = rank - excl, cum = 0;
      for (int j = 0; j < g; ++j) {
        unsigned int c = hist[tid * g + j];
        if (r < cum + c) { *sB = (unsigned int)(tid * g + j); *sR = r - cum; break; }
        cum += c;
      }
    }
  }
}

// ---- Kernel 2: exact rank select + bbox finalize -> grid params ------------
__global__ __launch_bounds__(256) void k_sel(
    const unsigned int* __restrict__ key, const int* __restrict__ pnum_p,
    const float4* __restrict__ blockmin, const float4* __restrict__ blockmax,
    float* __restrict__ thr_out, float* __restrict__ gparams, int L, int nbp) {
  __shared__ unsigned int hist[2048];
  __shared__ unsigned int sB, sR;
  int tid = threadIdx.x;
  unsigned int rank = (unsigned int)(L - pnum_p[0] - 1);
  const uint4* k4 = (const uint4*)key;
  int n4 = L >> 2;
  for (int b = tid; b < 2048; b += 256) hist[b] = 0u;
  __syncthreads();
  for (int i = tid; i < n4; i += 256) {
    uint4 v = k4[i];
    atomicAdd(&hist[v.x >> 21], 1u); atomicAdd(&hist[v.y >> 21], 1u);
    atomicAdd(&hist[v.z >> 21], 1u); atomicAdd(&hist[v.w >> 21], 1u);
  }
  __syncthreads();
  select_bin(hist, 2048, rank, &sB, &sR, tid);
  __syncthreads();
  unsigned int B1 = sB, R1 = sR;
  for (int b = tid; b < 2048; b += 256) hist[b] = 0u;
  __syncthreads();
  for (int i = tid; i < n4; i += 256) {
    uint4 v = k4[i];
    if ((v.x >> 21) == B1) atomicAdd(&hist[(v.x >> 10) & 2047u], 1u);
    if ((v.y >> 21) == B1) atomicAdd(&hist[(v.y >> 10) & 2047u], 1u);
    if ((v.z >> 21) == B1) atomicAdd(&hist[(v.z >> 10) & 2047u], 1u);
    if ((v.w >> 21) == B1) atomicAdd(&hist[(v.w >> 10) & 2047u], 1u);
  }
  __syncthreads();
  select_bin(hist, 2048, R1, &sB, &sR, tid);
  __syncthreads();
  unsigned int B2 = sB, R2 = sR;
  for (int b = tid; b < 1024; b += 256) hist[b] = 0u;
  __syncthreads();
  unsigned int top22 = (B1 << 11) | B2;
  for (int i = tid; i < n4; i += 256) {
    uint4 v = k4[i];
    if ((v.x >> 10) == top22) atomicAdd(&hist[v.x & 1023u], 1u);
    if ((v.y >> 10) == top22) atomicAdd(&hist[v.y & 1023u], 1u);
    if ((v.z >> 10) == top22) atomicAdd(&hist[v.z & 1023u], 1u);
    if ((v.w >> 10) == top22) atomicAdd(&hist[v.w & 1023u], 1u);
  }
  __syncthreads();
  select_bin(hist, 1024, R2, &sB, &sR, tid);
  __syncthreads();
  if (tid == 0) {
    unsigned int fkey = (B1 << 21) | (B2 << 10) | sB;
    unsigned int fb = (fkey & 0x80000000u) ? (fkey & 0x7FFFFFFFu) : ~fkey;
    thr_out[0] = __uint_as_float(fb);
  }
  // bbox reduce over per-block results -> grid params
  if (tid < 64) {
    float mnx = 3e38f, mny = 3e38f, mnz = 3e38f;
    float mxx = -3e38f, mxy = -3e38f, mxz = -3e38f;
    if (tid < nbp) {
      float4 mn = blockmin[tid], mx = blockmax[tid];
      mnx = mn.x; mny = mn.y; mnz = mn.z;
      mxx = mx.x; mxy = mx.y; mxz = mx.z;
    }
    #pragma unroll
    for (int o = 32; o > 0; o >>= 1) {
      mnx = fminf(mnx, __shfl_xor(mnx, o)); mny = fminf(mny, __shfl_xor(mny, o));
      mnz = fminf(mnz, __shfl_xor(mnz, o)); mxx = fmaxf(mxx, __shfl_xor(mxx, o));
      mxy = fmaxf(mxy, __shfl_xor(mxy, o)); mxz = fmaxf(mxz, __shfl_xor(mxz, o));
    }
    if (tid == 0) {
      float sx = fmaxf(mxx - mnx, 1e-9f);
      float sy = fmaxf(mxy - mny, 1e-9f);
      float sz = fmaxf(mxz - mnz, 1e-9f);
      gparams[0] = mnx; gparams[1] = mny; gparams[2] = mnz;
      gparams[3] = sx / GR; gparams[4] = sy / GR; gparams[5] = sz / GR;
      gparams[6] = GR / sx; gparams[7] = GR / sy; gparams[8] = GR / sz;
    }
  }
}

// ---- Kernel 3: keep mask + compaction + BCE + cell histograms --------------
__global__ __launch_bounds__(256) void k_keepc(
    const float* __restrict__ pred, const unsigned char* __restrict__ islm,
    const float* __restrict__ thr_p, const float* __restrict__ cxyz,
    const float* __restrict__ txyz, const int* __restrict__ ktgt,
    const float* __restrict__ gparams, int* __restrict__ keep,
    float4* __restrict__ klist, int* __restrict__ kidx,
    unsigned int* __restrict__ chist, unsigned int* __restrict__ thist,
    int* __restrict__ counters, float* __restrict__ out, int L, int N) {
  int i = blockIdx.x * 256 + threadIdx.x;
  float thr = thr_p[0];
  float term = 0.f;
  if (i < L) {
    float p = pred[i];
    bool kp = (p > thr) || islm[i];
    keep[i] = kp ? 1 : 0;
    if (kp) {
      int pos = atomicAdd(&counters[0], 1);   // order irrelevant (no ties)
      float x = cxyz[3*i], y = cxyz[3*i+1], z = cxyz[3*i+2];
      klist[pos] = make_float4(x, y, z, 0.f);
      kidx[pos] = i;
      atomicAdd(&chist[cell_of(x, y, z, gparams)], 1u);
    }
    float t = (float)ktgt[i];
    term = fmaxf(p, 0.f) - p * t + log1pf(expf(-fabsf(p)));
  }
  if (i < N) {
    atomicAdd(&thist[cell_of(txyz[3*i], txyz[3*i+1], txyz[3*i+2], gparams)], 1u);
  }
  for (int o = 32; o > 0; o >>= 1) term += __shfl_down(term, o);
  if ((threadIdx.x & 63) == 0) atomicAdd(&out[0], term);
}

// ---- Kernel 4: exclusive prefix sums for both grids (1 block) --------------
__global__ __launch_bounds__(256) void k_pfx(
    const unsigned int* __restrict__ chist, const unsigned int* __restrict__ thist,
    int* __restrict__ cstart, int* __restrict__ tstart,
    int* __restrict__ ccur, int* __restrict__ tcur) {
  __shared__ unsigned int wsum[4];
  int tid = threadIdx.x, lane = tid & 63, wv = tid >> 6;
  const int NC = GR * GR * GR;       // 4096
  const int PER = NC / 256;          // 16
  for (int h = 0; h < 2; ++h) {
    const unsigned int* hist = h ? thist : chist;
    int* st = h ? tstart : cstart;
    int* cur = h ? tcur : ccur;
    unsigned int loc[PER];
    unsigned int s = 0;
    int base = tid * PER;
    #pragma unroll
    for (int j = 0; j < PER; ++j) { loc[j] = s; s += hist[base + j]; }
    unsigned int incl = s;
    for (int o = 1; o < 64; o <<= 1) {
      unsigned int v = __shfl_up(incl, o);
      if (lane >= o) incl += v;
    }
    if (lane == 63) wsum[wv] = incl;
    __syncthreads();
    unsigned int woff = 0;
    for (int w = 0; w < wv; ++w) woff += wsum[w];
    unsigned int excl = woff + incl - s;
    #pragma unroll
    for (int j = 0; j < PER; ++j) {
      int v = (int)(excl + loc[j]);
      st[base + j] = v; cur[base + j] = v;
    }
    if (tid == 255) st[NC] = (int)(excl + s);
    __syncthreads();
  }
}

// ---- Kernel 5: counting-sort scatter into cell-ordered arrays --------------
__global__ __launch_bounds__(256) void k_sort(
    const float4* __restrict__ klist, const int* __restrict__ kidx,
    const int* __restrict__ counters, const float* __restrict__ txyz,
    const float* __restrict__ gparams, int* __restrict__ ccur,
    int* __restrict__ tcur, float4* __restrict__ csorted,
    float4* __restrict__ tsorted, int N) {
  int kc = counters[0];
  int gidx = blockIdx.x * 256 + threadIdx.x;
  int gsz = (int)gridDim.x * 256;
  for (int i = gidx; i < kc; i += gsz) {
    float4 cd = klist[i];
    int cid = cell_of(cd.x, cd.y, cd.z, gparams);
    int pos = atomicAdd(&ccur[cid], 1);
    csorted[pos] = make_float4(cd.x, cd.y, cd.z, __int_as_float(kidx[i]));
  }
  for (int i = gidx; i < N; i += gsz) {
    float x = txyz[3*i], y = txyz[3*i+1], z = txyz[3*i+2];
    int cid = cell_of(x, y, z, gparams);
    int pos = atomicAdd(&tcur[cid], 1);
    tsorted[pos] = make_float4(x, y, z, __int_as_float(i));
  }
}

// ---- Kernel 6: dual-role grid NN (backward + forward), plain stores --------
__global__ __launch_bounds__(256) void k_nn(
    const float4* __restrict__ csorted, const int* __restrict__ cstart,
    const float4* __restrict__ tsorted, const int* __restrict__ tstart,
    const int* __restrict__ counters, const float* __restrict__ gparams,
    ull* __restrict__ tmin, int* __restrict__ fidx, int L, int N) {
  int q = blockIdx.x * 256 + threadIdx.x;
  int kc = counters[0];
  float gp[9];
  #pragma unroll
  for (int j = 0; j < 9; ++j) gp[j] = gparams[j];
  if (q < N) {
    // backward: sorted target q -> NN among kept candidates
    float4 Q = tsorted[q];
    float best; int bi;
    nn_search(Q.x, Q.y, Q.z, cstart, csorted, gp, &best, &bi);
    int t = __float_as_int(Q.w);
    tmin[t] = ((ull)__float_as_uint(best) << 32) | (unsigned int)bi;
  } else {
    int f = q - N;
    if (f < kc) {
      // forward: sorted kept candidate f -> NN among targets
      float4 Q = csorted[f];
      float best; int bi;
      nn_search(Q.x, Q.y, Q.z, tstart, tsorted, gp, &best, &bi);
      fidx[__float_as_int(Q.w)] = bi;
    }
  }
}

// ---- Kernel 7: scatter weighted colors into num/den ------------------------
__global__ __launch_bounds__(256) void k_scatter(
    const float* __restrict__ trgb, const ull* __restrict__ tmin,
    float4* __restrict__ numden, int* __restrict__ zerohit,
    float4* __restrict__ zcolor, int N) {
  int t = blockIdx.x * 256 + threadIdx.x;
  if (t >= N) return;
  ull pack = tmin[t];
  float d = __uint_as_float((unsigned int)(pack >> 32));
  int idx = (int)(pack & 0xFFFFFFFFull);
  float r = trgb[3*t], g = trgb[3*t+1], b = trgb[3*t+2];
  if (d == 0.0f) {
    zerohit[idx] = 1;
    zcolor[idx] = make_float4(r, g, b, 0.f);
  } else {
    float w = 1.0f / sqrtf(fmaxf(d, 1e-30f));
    atomicAdd(&numden[idx].x, r * w);
    atomicAdd(&numden[idx].y, g * w);
    atomicAdd(&numden[idx].z, b * w);
    atomicAdd(&numden[idx].w, w);
  }
}

// ---- Kernel 8: final recolor select + L1 reduce ----------------------------
__global__ __launch_bounds__(256) void k_loss(
    const float* __restrict__ crgb, const float* __restrict__ trgb,
    const int* __restrict__ keep, const float4* __restrict__ numden,
    const int* __restrict__ zerohit, const float4* __restrict__ zcolor,
    const int* __restrict__ fidx, float* __restrict__ out, int L) {
  int l = blockIdx.x * 256 + threadIdx.x;
  float loss = 0.f;
  if (l < L && keep[l]) {
    float rr, rg, rb;
    if (zerohit[l]) {
      float4 z = zcolor[l]; rr = z.x; rg = z.y; rb = z.z;
    } else {
      float4 nd = numden[l];
      if (nd.w != 0.f) { rr = nd.x / nd.w; rg = nd.y / nd.w; rb = nd.z / nd.w; }
      else {
        int ti = fidx[l];
        rr = trgb[3*ti]; rg = trgb[3*ti+1]; rb = trgb[3*ti+2];
      }
    }
    float sr = crgb[3*l]*255.f, sg = crgb[3*l+1]*255.f, sb = crgb[3*l+2]*255.f;
    loss = fabsf(sr - rr) + fabsf(sg - rg) + fabsf(sb - rb);
  }
  for (int o = 32; o > 0; o >>= 1) loss += __shfl_down(loss, o);
  if ((threadIdx.x & 63) == 0) atomicAdd(&out[1], loss);
}

extern "C" void kernel_launch(void* const* d_in, const int* in_sizes, int n_in,
                              void* d_out, int out_size, void* d_ws, size_t ws_size,
                              hipStream_t stream) {
  const float* pred = (const float*)d_in[0];
  const float* cxyz = (const float*)d_in[1];
  const float* crgb = (const float*)d_in[2];
  const float* txyz = (const float*)d_in[3];
  const float* trgb = (const float*)d_in[4];
  const int*   ktgt = (const int*)d_in[5];
  const int*   pnum = (const int*)d_in[6];
  int L = in_sizes[0];
  int N = in_sizes[3] / 3;
  const int NC = GR * GR * GR;     // 4096

  // workspace layout: 16B arrays first, then 8B, 4B, bytes
  char* ws = (char*)d_ws;
  size_t off = 0;
  float4* klist   = (float4*)(ws + off);  off += (size_t)L * 16;
  float4* csorted = (float4*)(ws + off);  off += (size_t)L * 16;
  float4* tsorted = (float4*)(ws + off);  off += (size_t)((N + 3) & ~3) * 16;
  float4* numden  = (float4*)(ws + off);  off += (size_t)L * 16;
  float4* zcolor  = (float4*)(ws + off);  off += (size_t)L * 16;
  float4* blockmin = (float4*)(ws + off); off += 64 * 16;
  float4* blockmax = (float4*)(ws + off); off += 64 * 16;
  unsigned int* key = (unsigned int*)(ws + off); off += (size_t)L * 4;  // uint4-aligned
  ull* tmin       = (ull*)(ws + off);     off += (size_t)((N + 1) & ~1) * 8;
  int* keep       = (int*)(ws + off);     off += (size_t)L * 4;
  int* kidx       = (int*)(ws + off);     off += (size_t)L * 4;
  int* zerohit    = (int*)(ws + off);     off += (size_t)L * 4;
  int* fidx       = (int*)(ws + off);     off += (size_t)L * 4;
  unsigned int* chist = (unsigned int*)(ws + off); off += NC * 4;
  unsigned int* thist = (unsigned int*)(ws + off); off += NC * 4;
  int* cstart     = (int*)(ws + off);     off += (NC + 1) * 4;
  int* tstart     = (int*)(ws + off);     off += (NC + 1) * 4;
  int* ccur       = (int*)(ws + off);     off += NC * 4;
  int* tcur       = (int*)(ws + off);     off += NC * 4;
  float* gparams  = (float*)(ws + off);   off += 16 * 4;
  float* thr_slot = (float*)(ws + off);   off += 16;
  int* counters   = (int*)(ws + off);     off += 256;   // [0]=kcount
  unsigned char* islm = (unsigned char*)(ws + off); off += ((size_t)L + 15) & ~15ull;
  float* out = (float*)d_out;

  int nbL = (L + 255) / 256;       // 64
  int nbN = (N + 255) / 256;       // 40
  int mx = max(L, N);
  int nbp = (mx + 255) / 256;      // 64 (k_prep grid, <=64 for select reduce)

  k_prep<<<nbp, 256, 0, stream>>>(
      pred, txyz, cxyz, numden, zerohit, key, islm, chist, thist,
      blockmin, blockmax, counters, out, L, N);

  k_sel<<<1, 256, 0, stream>>>(
      key, pnum, blockmin, blockmax, thr_slot, gparams, L, nbp);

  k_keepc<<<nbL, 256, 0, stream>>>(
      pred, islm, thr_slot, cxyz, txyz, ktgt, gparams,
      keep, klist, kidx, chist, thist, counters, out, L, N);

  k_pfx<<<1, 256, 0, stream>>>(chist, thist, cstart, tstart, ccur, tcur);

  k_sort<<<nbL, 256, 0, stream>>>(
      klist, kidx, counters, txyz, gparams, ccur, tcur, csorted, tsorted, N);

  k_nn<<<(N + L + 255) / 256, 256, 0, stream>>>(
      csorted, cstart, tsorted, tstart, counters, gparams, tmin, fidx, L, N);

  k_scatter<<<nbN, 256, 0, stream>>>(trgb, tmin, numden, zerohit, zcolor, N);

  k_loss<<<nbL, 256, 0, stream>>>(
      crgb, trgb, keep, numden, zerohit, zcolor, fidx, out, L);
}

// Round 13
// 140.607 us; speedup vs baseline: 2.2333x; 2.2333x over previous
//
#include <hip/hip_runtime.h>
#include <hip/hip_bf16.h>

// Decoder loss: keep-mask (kth-value threshold + local max), BCE coord loss,
// bidirectional NN recolor + L1 rgb loss.
// L=16384 candidates, N=10000 targets, K=8 (collapses to argmin; R1-proven).
// R13: R10 chain + register-double-buffered transposed scan. Rules learned:
//   - Brute-force scan: broadcast-LDS 42us (dual-pipe-bound), transposed-LDS
//     44.7us (45% barrier-drain), global-stream 47.6us (L2), grid-NN 196us
//     (divergent latency chains, 1.7% occupancy — never again).
//   - Transposed scan is VALU-bound (~25us busy); the stall is the
//     single-buffered staging. Fix: reg-prefetch next tile during compute.
//   - grid.sync ~40us (R4); mass __threadfence ~0.4ms (R7); spin-fusion
//     neutral (R9). Kernel boundary ~5us is the cheap sync.

#define CH 1024      // staged chunk (16 KB LDS), PER=CH/256=4
typedef unsigned long long ull;

// ---- Kernel 1: init + monotone keys + per-8 local max ----------------------
__global__ __launch_bounds__(256) void k_prep(
    const float* __restrict__ pred, const float* __restrict__ txyz,
    float4* __restrict__ ttile, float4* __restrict__ numden,
    int* __restrict__ zerohit, unsigned int* __restrict__ key,
    unsigned char* __restrict__ islm, int* __restrict__ counters,
    float* __restrict__ out, int L, int N) {
  int gidx = blockIdx.x * 256 + threadIdx.x;
  int gsz = (int)gridDim.x * 256;
  for (int i = gidx; i < N; i += gsz) {
    float x = txyz[3*i], y = txyz[3*i+1], z = txyz[3*i+2];
    ttile[i] = make_float4(x, y, z, fmaf(x, x, fmaf(y, y, z * z)));
  }
  for (int i = gidx; i < L; i += gsz) {
    numden[i] = make_float4(0.f, 0.f, 0.f, 0.f);
    zerohit[i] = 0;
  }
  if (gidx < 8) counters[gidx] = 0;
  if (gidx < 2) out[gidx] = 0.f;
  int ngroups = L >> 3;
  for (int g = gidx; g < ngroups; g += gsz) {
    const float4* pv = (const float4*)pred + (size_t)g * 2;
    float4 a = pv[0], b = pv[1];
    float v[8] = {a.x, a.y, a.z, a.w, b.x, b.y, b.z, b.w};
    int bi = 0; float bv = v[0];
    #pragma unroll
    for (int j = 1; j < 8; ++j) if (v[j] > bv) { bv = v[j]; bi = j; }
    unsigned int kk[8];
    ull lmpack = 0ull;
    #pragma unroll
    for (int j = 0; j < 8; ++j) {
      unsigned int fb = __float_as_uint(v[j]);
      unsigned int mk = (fb & 0x80000000u) ? ~fb : (fb | 0x80000000u);
      if (j == bi) { mk = 0xFF800000u; lmpack |= 1ull << (8 * j); }  // +inf
      kk[j] = mk;
    }
    ((uint4*)key)[g*2]   = make_uint4(kk[0], kk[1], kk[2], kk[3]);
    ((uint4*)key)[g*2+1] = make_uint4(kk[4], kk[5], kk[6], kk[7]);
    *(ull*)(islm + (size_t)g * 8) = lmpack;
  }
}

// ---- helper: pick bin containing rank from LDS hist (wave 0) ---------------
__device__ __forceinline__ void select_bin(
    unsigned int* hist, int nb, unsigned int rank,
    unsigned int* sB, unsigned int* sR, int tid) {
  if (tid < 64) {
    int g = nb >> 6;
    unsigned int sum = 0;
    for (int j = 0; j < g; ++j) sum += hist[tid * g + j];
    unsigned int incl = sum;
    for (int o = 1; o < 64; o <<= 1) {
      unsigned int v = __shfl_up(incl, o);
      if (tid >= o) incl += v;
    }
    unsigned int excl = incl - sum;
    bool cond = (rank >= excl) && (rank < incl);
    unsigned long long bal = __ballot(cond);
    int first = __ffsll((long long)bal) - 1;
    if (tid == first) {
      unsigned int r = rank - excl, cum = 0;
      for (int j = 0; j < g; ++j) {
        unsigned int c = hist[tid * g + j];
        if (r < cum + c) { *sB = (unsigned int)(tid * g + j); *sR = r - cum; break; }
        cum += c;
      }
    }
  }
}

// ---- Kernel 2: exact rank select, self-contained (1 block, 3 sweeps) -------
__global__ __launch_bounds__(256) void k_sel(
    const unsigned int* __restrict__ key, const int* __restrict__ pnum_p,
    float* __restrict__ thr_out, int L) {
  __shared__ unsigned int hist[2048];
  __shared__ unsigned int sB, sR;
  int tid = threadIdx.x;
  unsigned int rank = (unsigned int)(L - pnum_p[0] - 1);
  const uint4* k4 = (const uint4*)key;
  int n4 = L >> 2;
  for (int b = tid; b < 2048; b += 256) hist[b] = 0u;
  __syncthreads();
  for (int i = tid; i < n4; i += 256) {
    uint4 v = k4[i];
    atomicAdd(&hist[v.x >> 21], 1u); atomicAdd(&hist[v.y >> 21], 1u);
    atomicAdd(&hist[v.z >> 21], 1u); atomicAdd(&hist[v.w >> 21], 1u);
  }
  __syncthreads();
  select_bin(hist, 2048, rank, &sB, &sR, tid);
  __syncthreads();
  unsigned int B1 = sB, R1 = sR;
  for (int b = tid; b < 2048; b += 256) hist[b] = 0u;
  __syncthreads();
  for (int i = tid; i < n4; i += 256) {
    uint4 v = k4[i];
    if ((v.x >> 21) == B1) atomicAdd(&hist[(v.x >> 10) & 2047u], 1u);
    if ((v.y >> 21) == B1) atomicAdd(&hist[(v.y >> 10) & 2047u], 1u);
    if ((v.z >> 21) == B1) atomicAdd(&hist[(v.z >> 10) & 2047u], 1u);
    if ((v.w >> 21) == B1) atomicAdd(&hist[(v.w >> 10) & 2047u], 1u);
  }
  __syncthreads();
  select_bin(hist, 2048, R1, &sB, &sR, tid);
  __syncthreads();
  unsigned int B2 = sB, R2 = sR;
  for (int b = tid; b < 1024; b += 256) hist[b] = 0u;
  __syncthreads();
  unsigned int top22 = (B1 << 11) | B2;
  for (int i = tid; i < n4; i += 256) {
    uint4 v = k4[i];
    if ((v.x >> 10) == top22) atomicAdd(&hist[v.x & 1023u], 1u);
    if ((v.y >> 10) == top22) atomicAdd(&hist[v.y & 1023u], 1u);
    if ((v.z >> 10) == top22) atomicAdd(&hist[v.z & 1023u], 1u);
    if ((v.w >> 10) == top22) atomicAdd(&hist[v.w & 1023u], 1u);
  }
  __syncthreads();
  select_bin(hist, 1024, R2, &sB, &sR, tid);
  __syncthreads();
  if (tid == 0) {
    unsigned int fkey = (B1 << 21) | (B2 << 10) | sB;
    unsigned int fb = (fkey & 0x80000000u) ? (fkey & 0x7FFFFFFFu) : ~fkey;
    thr_out[0] = __uint_as_float(fb);
  }
}

// ---- Kernel 3: keep mask + compaction + BCE reduce -------------------------
__global__ __launch_bounds__(256) void k_keepc(
    const float* __restrict__ pred, const unsigned char* __restrict__ islm,
    const float* __restrict__ thr_p, const float* __restrict__ cxyz,
    const int* __restrict__ ktgt, int* __restrict__ keep,
    float4* __restrict__ klist, int* __restrict__ kidx,
    int* __restrict__ counters, float* __restrict__ out, int L) {
  int i = blockIdx.x * 256 + threadIdx.x;
  float thr = thr_p[0];
  float term = 0.f;
  if (i < L) {
    float p = pred[i];
    bool kp = (p > thr) || islm[i];
    keep[i] = kp ? 1 : 0;
    if (kp) {
      int pos = atomicAdd(&counters[0], 1);   // order irrelevant (no ties)
      float x = cxyz[3*i], y = cxyz[3*i+1], z = cxyz[3*i+2];
      klist[pos] = make_float4(x, y, z, fmaf(x, x, fmaf(y, y, z * z)));
      kidx[pos] = i;
    }
    float t = (float)ktgt[i];
    term = fmaxf(p, 0.f) - p * t + log1pf(expf(-fabsf(p)));
  }
  for (int o = 32; o > 0; o >>= 1) term += __shfl_down(term, o);
  if ((threadIdx.x & 63) == 0) atomicAdd(&out[0], term);
}

// ---- Kernel 4: transposed dual-role scan, register-double-buffered ---------
// Wave owns 4 queries; lanes sweep the staged tile (1 per-lane ds_read_b128
// per 64 evals). Next tile prefetched into registers during compute, so the
// end-of-tile barrier no longer drains global loads (R10's 45% stall).
__global__ __launch_bounds__(256) void k_scanw(
    const float* __restrict__ txyz, const float4* __restrict__ klist,
    const int* __restrict__ kidx, const float4* __restrict__ ttile,
    const int* __restrict__ counters, ull* __restrict__ tmin,
    int* __restrict__ fidx, int L, int N, int NBW) {
  __shared__ float4 sb[CH];
  int tid = threadIdx.x;
  int lane = tid & 63;
  int wv = tid >> 6;
  int kc = counters[0];
  int bid = blockIdx.x;

  float q0x, q0y, q0z, q1x, q1y, q1z, q2x, q2y, q2z, q3x, q3y, q3z;
  const float4* list; int listn; int q0;
  if (bid < NBW) {           // backward: queries = targets, list = klist
    q0 = bid * 16 + wv * 4;
    int a = min(q0, N - 1), b = min(q0 + 1, N - 1),
        c = min(q0 + 2, N - 1), d = min(q0 + 3, N - 1);
    q0x = txyz[3*a]; q0y = txyz[3*a+1]; q0z = txyz[3*a+2];
    q1x = txyz[3*b]; q1y = txyz[3*b+1]; q1z = txyz[3*b+2];
    q2x = txyz[3*c]; q2y = txyz[3*c+1]; q2z = txyz[3*c+2];
    q3x = txyz[3*d]; q3y = txyz[3*d+1]; q3z = txyz[3*d+2];
    list = klist; listn = kc;
  } else {                   // forward: queries = kept candidates, list = ttile
    int eb = (bid - NBW) * 16;
    if (eb >= kc) return;    // uniform early-exit
    q0 = eb + wv * 4;
    int a = min(q0, kc - 1), b = min(q0 + 1, kc - 1),
        c = min(q0 + 2, kc - 1), d = min(q0 + 3, kc - 1);
    float4 A = klist[a], B = klist[b], C = klist[c], D = klist[d];
    q0x = A.x; q0y = A.y; q0z = A.z;
    q1x = B.x; q1y = B.y; q1z = B.z;
    q2x = C.x; q2y = C.y; q2z = C.z;
    q3x = D.x; q3y = D.y; q3z = D.z;
    list = ttile; listn = N;
  }
  float n0x = -2.f*q0x, n0y = -2.f*q0y, n0z = -2.f*q0z;
  float n1x = -2.f*q1x, n1y = -2.f*q1y, n1z = -2.f*q1z;
  float n2x = -2.f*q2x, n2y = -2.f*q2y, n2z = -2.f*q2z;
  float n3x = -2.f*q3x, n3y = -2.f*q3y, n3z = -2.f*q3z;
  float b0 = 3e38f, b1 = 3e38f, b2 = 3e38f, b3 = 3e38f;
  int i0 = 0, i1 = 0, i2 = 0, i3 = 0;

  int nt = (listn + CH - 1) / CH;
  float4 r[4];
  #pragma unroll
  for (int j = 0; j < 4; ++j) {
    int idx = tid + j * 256;
    r[j] = (idx < listn) ? list[idx] : make_float4(0.f, 0.f, 0.f, 3e38f);
  }
  for (int t = 0; t < nt; ++t) {
    __syncthreads();                       // prev compute done before overwrite
    #pragma unroll
    for (int j = 0; j < 4; ++j) sb[tid + j * 256] = r[j];
    __syncthreads();
    if (t + 1 < nt) {                      // prefetch next tile during compute
      int base = (t + 1) * CH;
      #pragma unroll
      for (int j = 0; j < 4; ++j) {
        int idx = base + tid + j * 256;
        r[j] = (idx < listn) ? list[idx] : make_float4(0.f, 0.f, 0.f, 3e38f);
      }
    }
    int cnt = min(CH, listn - t * CH);
    int cntp = (cnt + 63) & ~63;
    #pragma unroll 2
    for (int i = lane; i < cntp; i += 64) {
      float4 A = sb[i];
      int c = t * CH + i;
      // monotone surrogate |p|^2 - 2 q.p (argmin-equiv to |q-p|^2); pad w=3e38
      float d0 = fmaf(n0x, A.x, A.w); d0 = fmaf(n0y, A.y, d0); d0 = fmaf(n0z, A.z, d0);
      float d1 = fmaf(n1x, A.x, A.w); d1 = fmaf(n1y, A.y, d1); d1 = fmaf(n1z, A.z, d1);
      float d2 = fmaf(n2x, A.x, A.w); d2 = fmaf(n2y, A.y, d2); d2 = fmaf(n2z, A.z, d2);
      float d3 = fmaf(n3x, A.x, A.w); d3 = fmaf(n3y, A.y, d3); d3 = fmaf(n3z, A.z, d3);
      if (d0 < b0) { b0 = d0; i0 = c; }
      if (d1 < b1) { b1 = d1; i1 = c; }
      if (d2 < b2) { b2 = d2; i2 = c; }
      if (d3 < b3) { b3 = d3; i3 = c; }
    }
  }
  // wave argmin reduce (prefer lower index on exact tie, matching jnp)
  #pragma unroll
  for (int o = 32; o > 0; o >>= 1) {
    float ob; int oi;
    ob = __shfl_xor(b0, o); oi = __shfl_xor(i0, o);
    if (ob < b0 || (ob == b0 && oi < i0)) { b0 = ob; i0 = oi; }
    ob = __shfl_xor(b1, o); oi = __shfl_xor(i1, o);
    if (ob < b1 || (ob == b1 && oi < i1)) { b1 = ob; i1 = oi; }
    ob = __shfl_xor(b2, o); oi = __shfl_xor(i2, o);
    if (ob < b2 || (ob == b2 && oi < i2)) { b2 = ob; i2 = oi; }
    ob = __shfl_xor(b3, o); oi = __shfl_xor(i3, o);
    if (ob < b3 || (ob == b3 && oi < i3)) { b3 = ob; i3 = oi; }
  }
  if (lane == 0) {
    int ii[4] = {i0, i1, i2, i3};
    if (bid < NBW) {
      #pragma unroll
      for (int j = 0; j < 4; ++j) {
        int t = q0 + j;
        if (t < N) {
          float4 cd = klist[ii[j]];
          float dx = txyz[3*t] - cd.x, dy = txyz[3*t+1] - cd.y, dz = txyz[3*t+2] - cd.z;
          float dtrue = fmaf(dx, dx, fmaf(dy, dy, dz * dz));  // exact (R1-proven)
          tmin[t] = ((ull)__float_as_uint(dtrue) << 32) | (unsigned int)kidx[ii[j]];
        }
      }
    } else {
      #pragma unroll
      for (int j = 0; j < 4; ++j) {
        int e = q0 + j;
        if (e < kc) fidx[kidx[e]] = ii[j];
      }
    }
  }
}

// ---- Kernel 5: scatter weighted colors into num/den ------------------------
__global__ __launch_bounds__(256) void k_scatter(
    const float* __restrict__ trgb, const ull* __restrict__ tmin,
    float4* __restrict__ numden, int* __restrict__ zerohit,
    float4* __restrict__ zcolor, int N) {
  int t = blockIdx.x * 256 + threadIdx.x;
  if (t >= N) return;
  ull pack = tmin[t];
  float d = __uint_as_float((unsigned int)(pack >> 32));
  int idx = (int)(pack & 0xFFFFFFFFull);
  float r = trgb[3*t], g = trgb[3*t+1], b = trgb[3*t+2];
  if (d == 0.0f) {
    zerohit[idx] = 1;
    zcolor[idx] = make_float4(r, g, b, 0.f);
  } else {
    float w = 1.0f / sqrtf(fmaxf(d, 1e-30f));
    atomicAdd(&numden[idx].x, r * w);
    atomicAdd(&numden[idx].y, g * w);
    atomicAdd(&numden[idx].z, b * w);
    atomicAdd(&numden[idx].w, w);
  }
}

// ---- Kernel 6: final recolor select + L1 reduce ----------------------------
__global__ __launch_bounds__(256) void k_loss(
    const float* __restrict__ crgb, const float* __restrict__ trgb,
    const int* __restrict__ keep, const float4* __restrict__ numden,
    const int* __restrict__ zerohit, const float4* __restrict__ zcolor,
    const int* __restrict__ fidx, float* __restrict__ out, int L) {
  int l = blockIdx.x * 256 + threadIdx.x;
  float loss = 0.f;
  if (l < L && keep[l]) {
    float rr, rg, rb;
    if (zerohit[l]) {
      float4 z = zcolor[l]; rr = z.x; rg = z.y; rb = z.z;
    } else {
      float4 nd = numden[l];
      if (nd.w != 0.f) { rr = nd.x / nd.w; rg = nd.y / nd.w; rb = nd.z / nd.w; }
      else {
        int ti = fidx[l];
        rr = trgb[3*ti]; rg = trgb[3*ti+1]; rb = trgb[3*ti+2];
      }
    }
    float sr = crgb[3*l]*255.f, sg = crgb[3*l+1]*255.f, sb = crgb[3*l+2]*255.f;
    loss = fabsf(sr - rr) + fabsf(sg - rg) + fabsf(sb - rb);
  }
  for (int o = 32; o > 0; o >>= 1) loss += __shfl_down(loss, o);
  if ((threadIdx.x & 63) == 0) atomicAdd(&out[1], loss);
}

extern "C" void kernel_launch(void* const* d_in, const int* in_sizes, int n_in,
                              void* d_out, int out_size, void* d_ws, size_t ws_size,
                              hipStream_t stream) {
  const float* pred = (const float*)d_in[0];
  const float* cxyz = (const float*)d_in[1];
  const float* crgb = (const float*)d_in[2];
  const float* txyz = (const float*)d_in[3];
  const float* trgb = (const float*)d_in[4];
  const int*   ktgt = (const int*)d_in[5];
  const int*   pnum = (const int*)d_in[6];
  int L = in_sizes[0];
  int N = in_sizes[3] / 3;

  // workspace layout: 16B arrays first, then 8B, 4B, bytes
  char* ws = (char*)d_ws;
  size_t off = 0;
  float4* klist  = (float4*)(ws + off);   off += (size_t)L * 16;
  float4* ttile  = (float4*)(ws + off);   off += (size_t)((N + 3) & ~3) * 16;
  float4* numden = (float4*)(ws + off);   off += (size_t)L * 16;
  float4* zcolor = (float4*)(ws + off);   off += (size_t)L * 16;
  unsigned int* key = (unsigned int*)(ws + off); off += (size_t)L * 4;  // uint4-aligned
  ull* tmin      = (ull*)(ws + off);      off += (size_t)((N + 1) & ~1) * 8;
  int* keep      = (int*)(ws + off);      off += (size_t)L * 4;
  int* kidx      = (int*)(ws + off);      off += (size_t)L * 4;
  int* zerohit   = (int*)(ws + off);      off += (size_t)L * 4;
  int* fidx      = (int*)(ws + off);      off += (size_t)L * 4;
  float* thr_slot = (float*)(ws + off);   off += 16;
  int* counters  = (int*)(ws + off);      off += 256;   // [0]=kcount
  unsigned char* islm = (unsigned char*)(ws + off); off += ((size_t)L + 15) & ~15ull;
  float* out = (float*)d_out;

  int nbL = (L + 255) / 256;     // 64
  int nbN = (N + 255) / 256;     // 40
  int NBW = (N + 15) / 16;       // 625 backward blocks (16 queries each)
  int NFW = (L + 15) / 16;       // 1024 forward blocks max (early-exit at kc)
  int mx = max(L, N);

  k_prep<<<(mx + 255) / 256, 256, 0, stream>>>(
      pred, txyz, ttile, numden, zerohit, key, islm, counters, out, L, N);

  k_sel<<<1, 256, 0, stream>>>(key, pnum, thr_slot, L);

  k_keepc<<<nbL, 256, 0, stream>>>(
      pred, islm, thr_slot, cxyz, ktgt, keep, klist, kidx, counters, out, L);

  k_scanw<<<NBW + NFW, 256, 0, stream>>>(
      txyz, klist, kidx, ttile, counters, tmin, fidx, L, N, NBW);

  k_scatter<<<nbN, 256, 0, stream>>>(trgb, tmin, numden, zerohit, zcolor, N);

  k_loss<<<nbL, 256, 0, stream>>>(
      crgb, trgb, keep, numden, zerohit, zcolor, fidx, out, L);
}